// Round 9
// baseline (678.899 us; speedup 1.0000x reference)
//
#include <hip/hip_runtime.h>
#include <cstdint>
#include <cstddef>

#define HID 512
#define BATCH 4096
#define T_STEPS 20

typedef unsigned short ushort_t;
typedef __attribute__((ext_vector_type(8))) __bf16 bf16x8;
typedef __attribute__((ext_vector_type(4))) float f32x4;

typedef __attribute__((address_space(1))) void gvoid;
typedef __attribute__((address_space(3))) void lvoid;

// fp32 -> bf16 round-to-nearest-even (finite inputs only)
__device__ __forceinline__ unsigned short f2bf(float f) {
  unsigned int u = __float_as_uint(f);
  u += 0x7FFFu + ((u >> 16) & 1u);
  return (unsigned short)(u >> 16);
}

// async global->LDS, 16B per lane. lds ptr must be wave-uniform (lane*16 is added by HW).
__device__ __forceinline__ void load_lds16(const void* g, void* l) {
  __builtin_amdgcn_global_load_lds((gvoid*)g, (lvoid*)l, 16, 0, 0);
}

// wave-local counted vmcnt waits (in-order completion per wave)
#define WAITV6 do { asm volatile("s_waitcnt vmcnt(6)" ::: "memory"); __builtin_amdgcn_sched_barrier(0); } while (0)
#define WAITV4 do { asm volatile("s_waitcnt vmcnt(4)" ::: "memory"); __builtin_amdgcn_sched_barrier(0); } while (0)
#define WAITV0 do { asm volatile("s_waitcnt vmcnt(0)" ::: "memory"); __builtin_amdgcn_sched_barrier(0); } while (0)

// 1-ulp hardware reciprocal (v_rcp_f32) — avoids the ~8-op fp32 div sequence
__device__ __forceinline__ float frcp(float x) {
  float r; asm("v_rcp_f32 %0, %1" : "=v"(r) : "v"(x)); return r;
}
// fast sigmoid / tanh (saturate correctly: exp->inf => rcp->0)
__device__ __forceinline__ float fsigm(float x) { return frcp(1.f + __expf(-x)); }
__device__ __forceinline__ float ftanh(float x) { return 1.f - 2.f * frcp(__expf(2.f * x) + 1.f); }

// ---------------------------------------------------------------------------
// PERSISTENT fused ODE kernel — wave-local staging, barrier-free K-loops
// (round-8 skeleton, 647us) with the VALU/LDS diet:
//  * A-fragments (zbs) hoisted to 16 statically-indexed VGPR frags per step
//    (reused across all 4 ht tiles: -48 ds_read_b128/wave/step)
//  * load addressing = per-lane offsets precomputed once + uniform tile
//    offset (2 VALU/load instead of full 64-bit recompute)
//  * gate math via v_rcp/v_exp (libm tanhf + fp32 div were ~70 VALU/elem)
//  * GEMM2 B-swizzle widened to 8 bank-groups/quarter-wave (was 4-way)
// Structure/sync/vmcnt identical to round 8.
// ---------------------------------------------------------------------------
__global__ __launch_bounds__(512) void ode_persistent(
    const float* __restrict__ y,
    const ushort_t* __restrict__ Wcat,   // [3*512,512] bf16 row-major
    const ushort_t* __restrict__ WoutB,  // [512,512] bf16 row-major
    const float* __restrict__ bout,
    const float* __restrict__ Wfc, const float* __restrict__ bfc,
    const float* __restrict__ ts, float* __restrict__ out) {
  __shared__ ushort_t wst[2][8][3072];      // 96 KB: [buf][wave][6KB region]
  __shared__ ushort_t zbs[64 * 16 * 8];     // 16 KB  [kp][row][e] bf16(z)
  __shared__ ushort_t dhs[64 * 16 * 8];     // 16 KB  [kp][row][e] dh
  __shared__ float rmax1[8][16];
  __shared__ float rsum1[8][16];
  __shared__ float rmax2[8][16];
  __shared__ float rsd[8][16][2];
  __shared__ float dts[T_STEPS];

  const int tid = threadIdx.x;
  const int wave = tid >> 6;     // 0..7
  const int lane = tid & 63;
  const int quad = lane >> 4;
  const int l16 = lane & 15;
  const int m0 = blockIdx.x * 16;
  const int wn2 = wave * 64;     // epilogue/GEMM2 column base

  if (tid < T_STEPS - 1) dts[tid] = ts[tid + 1] - ts[tid];

  // constants per thread
  float boutr[4], wfcr[4];
#pragma unroll
  for (int j = 0; j < 4; ++j) {
    boutr[j] = bout[wn2 + j * 16 + l16];
    wfcr[j] = Wfc[wn2 + j * 16 + l16];
  }
  const float bfc0 = bfc[0];

  ushort_t* const w0 = &wst[0][wave][0];
  ushort_t* const w1 = &wst[1][wave][0];

  // --- per-lane load offsets (elements), computed ONCE ---
  // GEMM1: inst i: g=i>>1, c=(i&1)*8+(lane>>3), kc=(lane&7)^(c&7)
  //   element = g*512*512 + (wave*16+c)*512 + kc*8 ; tile adds (tt>>3)*65536+(tt&7)*64
  int loff1[6];
#pragma unroll
  for (int i = 0; i < 6; ++i) {
    int c = (i & 1) * 8 + (lane >> 3);
    int kc = (lane & 7) ^ (c & 7);
    loff1[i] = (i >> 1) * 262144 + (wave * 16 + c) * 512 + kc * 8;
  }
  // GEMM2: inst i: c=i*16+(lane>>2), kc=(lane&3)^((lane>>3)&3)
  //   element = (wave*64+c)*512 + kc*8 ; tile adds tt*32
  int loff2[4];
#pragma unroll
  for (int i = 0; i < 4; ++i) {
    int c = i * 16 + (lane >> 2);
    int kc = (lane & 3) ^ ((lane >> 3) & 3);
    loff2[i] = (wave * 64 + c) * 512 + kc * 8;
  }
  const int x7 = l16 & 7;          // GEMM1 B-read swizzle key
  const int x3b = (l16 >> 1) & 3;  // GEMM2 B-read swizzle key

  // z state: z[row=quad*4+r][col=wn2+j*16+l16] = zreg[j][r]
  f32x4 zreg[4];
#pragma unroll
  for (int j = 0; j < 4; ++j) {
    int col = wn2 + j * 16 + l16;
    int kp = col >> 3, ce = col & 7;
#pragma unroll
    for (int r = 0; r < 4; ++r) {
      float v = y[(size_t)(m0 + quad * 4 + r) * HID + col];
      zreg[j][r] = v;
      zbs[(kp * 16 + quad * 4 + r) * 8 + ce] = f2bf(v);
    }
  }

  auto proj_out = [&](int tcol) {
    float m2[4];
#pragma unroll
    for (int r = 0; r < 4; ++r) {
      float m = zreg[0][r];
#pragma unroll
      for (int j = 1; j < 4; ++j) m = fmaxf(m, zreg[j][r]);
#pragma unroll
      for (int off = 1; off < 16; off <<= 1) m = fmaxf(m, __shfl_xor(m, off));
      m2[r] = m;
    }
    if (l16 == 0) {
#pragma unroll
      for (int r = 0; r < 4; ++r) rmax2[wave][quad * 4 + r] = m2[r];
    }
    __syncthreads();
#pragma unroll
    for (int r = 0; r < 4; ++r) {
      int row = quad * 4 + r;
      float m = rmax2[0][row];
#pragma unroll
      for (int w = 1; w < 8; ++w) m = fmaxf(m, rmax2[w][row]);
      m2[r] = m;
    }
    float s2[4] = {0.f, 0.f, 0.f, 0.f};
    float dd[4] = {0.f, 0.f, 0.f, 0.f};
#pragma unroll
    for (int j = 0; j < 4; ++j)
#pragma unroll
      for (int r = 0; r < 4; ++r) {
        float e = __expf(zreg[j][r] - m2[r]);
        s2[r] += e;
        dd[r] += e * wfcr[j];
      }
#pragma unroll
    for (int r = 0; r < 4; ++r) {
#pragma unroll
      for (int off = 1; off < 16; off <<= 1) {
        s2[r] += __shfl_xor(s2[r], off);
        dd[r] += __shfl_xor(dd[r], off);
      }
    }
    if (l16 == 0) {
#pragma unroll
      for (int r = 0; r < 4; ++r) {
        rsd[wave][quad * 4 + r][0] = s2[r];
        rsd[wave][quad * 4 + r][1] = dd[r];
      }
    }
    __syncthreads();
    if (wave == 0 && l16 == 0) {
#pragma unroll
      for (int r = 0; r < 4; ++r) {
        int row = quad * 4 + r;
        float ss = 0.f, dv = 0.f;
#pragma unroll
        for (int w = 0; w < 8; ++w) { ss += rsd[w][row][0]; dv += rsd[w][row][1]; }
        out[(size_t)(m0 + row) * T_STEPS + tcol] = dv / ss + bfc0;
      }
    }
    __syncthreads();
  };

  // wave-local stages: uniform tile offset + per-lane precomputed offsets
  auto stage1n = [&](ushort_t* dst, int nt) {
    const ushort_t* pt = Wcat + ((nt >> 3) << 16) + ((nt & 7) << 6);
#pragma unroll
    for (int i = 0; i < 6; ++i)
      load_lds16(pt + loff1[i], dst + i * 512);
  };
  auto stage2n = [&](ushort_t* dst, int nt) {
    const ushort_t* pt = WoutB + nt * 32;
#pragma unroll
    for (int i = 0; i < 4; ++i)
      load_lds16(pt + loff2[i], dst + i * 512);
  };

  proj_out(0);

  // ======================= time loop =======================
  for (int t = 0; t < T_STEPS - 1; ++t) {
    // ---- A-fragments for the step: 16 statically-indexed regs ----
    bf16x8 afr[16];
#pragma unroll
    for (int kk = 0; kk < 8; ++kk) {
      afr[2 * kk]     = *(const bf16x8*)&zbs[((kk * 8 + quad) * 16 + l16) * 8];
      afr[2 * kk + 1] = *(const bf16x8*)&zbs[((kk * 8 + 4 + quad) * 16 + l16) * 8];
    }

    // ---- GEMM1: 4 ht x 8 k64-tiles, barrier-free, dbuf wave-local ----
    stage1n(w0, 0);
#pragma unroll 1
    for (int ht = 0; ht < 4; ++ht) {
      f32x4 a0 = {}, a1 = {}, a2 = {};
#pragma unroll
      for (int kk = 0; kk < 8; ++kk) {
        ushort_t* wc = (kk & 1) ? w1 : w0;
        ushort_t* wn = (kk & 1) ? w0 : w1;
        if (kk < 7) {
          stage1n(wn, ht * 8 + kk + 1); WAITV6;
        } else if (ht < 3) {
          stage1n(wn, ht * 8 + 8); WAITV6;
        } else {
          WAITV0;
        }
        bf16x8 b00 = *(const bf16x8*)&wc[(0 * 128 + l16 * 8 + (quad ^ x7)) * 8];
        bf16x8 b01 = *(const bf16x8*)&wc[(0 * 128 + l16 * 8 + ((quad + 4) ^ x7)) * 8];
        bf16x8 b10 = *(const bf16x8*)&wc[(1 * 128 + l16 * 8 + (quad ^ x7)) * 8];
        bf16x8 b11 = *(const bf16x8*)&wc[(1 * 128 + l16 * 8 + ((quad + 4) ^ x7)) * 8];
        bf16x8 b20 = *(const bf16x8*)&wc[(2 * 128 + l16 * 8 + (quad ^ x7)) * 8];
        bf16x8 b21 = *(const bf16x8*)&wc[(2 * 128 + l16 * 8 + ((quad + 4) ^ x7)) * 8];
        a0 = __builtin_amdgcn_mfma_f32_16x16x32_bf16(afr[2 * kk], b00, a0, 0, 0, 0);
        a0 = __builtin_amdgcn_mfma_f32_16x16x32_bf16(afr[2 * kk + 1], b01, a0, 0, 0, 0);
        a1 = __builtin_amdgcn_mfma_f32_16x16x32_bf16(afr[2 * kk], b10, a1, 0, 0, 0);
        a1 = __builtin_amdgcn_mfma_f32_16x16x32_bf16(afr[2 * kk + 1], b11, a1, 0, 0, 0);
        a2 = __builtin_amdgcn_mfma_f32_16x16x32_bf16(afr[2 * kk], b20, a2, 0, 0, 0);
        a2 = __builtin_amdgcn_mfma_f32_16x16x32_bf16(afr[2 * kk + 1], b21, a2, 0, 0, 0);
      }
      // activation -> dhs (wave's own cols: ht*128 + wave*16 + l16)
      {
        int col = ht * 128 + wave * 16 + l16;
        int kp = col >> 3, ce = col & 7;
#pragma unroll
        for (int r = 0; r < 4; ++r) {
          float gi = fsigm(a0[r]);
          float gg = ftanh(a1[r]);
          float go = fsigm(a2[r]);
          dhs[(kp * 16 + quad * 4 + r) * 8 + ce] = f2bf(go * ftanh(gi * gg));
        }
      }
    }
    __syncthreads();   // dhs visible to all waves

    // ---- GEMM2: 16 k32-tiles, barrier-free, dbuf wave-local ----
    f32x4 acc2[4] = {};
    stage2n(w0, 0);
#pragma unroll
    for (int tt = 0; tt < 16; ++tt) {
      ushort_t* wc = (tt & 1) ? w1 : w0;
      ushort_t* wn = (tt & 1) ? w0 : w1;
      if (tt + 1 < 16) { stage2n(wn, tt + 1); WAITV4; } else { WAITV0; }
      bf16x8 afd = *(const bf16x8*)&dhs[((tt * 4 + quad) * 16 + l16) * 8];
#pragma unroll
      for (int j = 0; j < 4; ++j) {
        bf16x8 bf = *(const bf16x8*)&wc[(((j * 16 + l16) * 4) + (quad ^ x3b)) * 8];
        acc2[j] = __builtin_amdgcn_mfma_f32_16x16x32_bf16(afd, bf, acc2[j], 0, 0, 0);
      }
    }

    // ---- epilogue: softmax(+bout), z += dt*s, zbs refresh, out proj ----
    const float dtv = dts[t];
#pragma unroll
    for (int j = 0; j < 4; ++j)
#pragma unroll
      for (int r = 0; r < 4; ++r) acc2[j][r] += boutr[j];

    float m1[4];
#pragma unroll
    for (int r = 0; r < 4; ++r) {
      float m = acc2[0][r];
#pragma unroll
      for (int j = 1; j < 4; ++j) m = fmaxf(m, acc2[j][r]);
#pragma unroll
      for (int off = 1; off < 16; off <<= 1) m = fmaxf(m, __shfl_xor(m, off));
      m1[r] = m;
    }
    if (l16 == 0) {
#pragma unroll
      for (int r = 0; r < 4; ++r) rmax1[wave][quad * 4 + r] = m1[r];
    }
    __syncthreads();
#pragma unroll
    for (int r = 0; r < 4; ++r) {
      int row = quad * 4 + r;
      float m = rmax1[0][row];
#pragma unroll
      for (int w = 1; w < 8; ++w) m = fmaxf(m, rmax1[w][row]);
      m1[r] = m;
    }

    float s1[4] = {0.f, 0.f, 0.f, 0.f};
#pragma unroll
    for (int j = 0; j < 4; ++j)
#pragma unroll
      for (int r = 0; r < 4; ++r) {
        float e = __expf(acc2[j][r] - m1[r]);
        acc2[j][r] = e;
        s1[r] += e;
      }
#pragma unroll
    for (int r = 0; r < 4; ++r) {
#pragma unroll
      for (int off = 1; off < 16; off <<= 1) s1[r] += __shfl_xor(s1[r], off);
    }
    if (l16 == 0) {
#pragma unroll
      for (int r = 0; r < 4; ++r) rsum1[wave][quad * 4 + r] = s1[r];
    }
    __syncthreads();
    float inv1[4];
#pragma unroll
    for (int r = 0; r < 4; ++r) {
      int row = quad * 4 + r;
      float s = rsum1[0][row];
#pragma unroll
      for (int w = 1; w < 8; ++w) s += rsum1[w][row];
      inv1[r] = 1.f / s;
    }

#pragma unroll
    for (int j = 0; j < 4; ++j) {
      int col = wn2 + j * 16 + l16;
      int kp = col >> 3, ce = col & 7;
#pragma unroll
      for (int r = 0; r < 4; ++r) {
        float zn = zreg[j][r] + dtv * acc2[j][r] * inv1[r];
        zreg[j][r] = zn;
        zbs[(kp * 16 + quad * 4 + r) * 8 + ce] = f2bf(zn);
      }
    }

    proj_out(t + 1);   // ends with __syncthreads: zbs visible for next GEMM1
  }
}

// weights fp32 -> bf16; Wcat = [Wi; Wg; Wo] (each 512x512, row-major => flat concat)
__global__ __launch_bounds__(256) void convw_kernel(
    const float* __restrict__ Wi, const float* __restrict__ Wg,
    const float* __restrict__ Wo, const float* __restrict__ Wout,
    ushort_t* __restrict__ Wcat, ushort_t* __restrict__ WoutB) {
  const int nW = HID * HID;  // 262144
  int e = (blockIdx.x * 256 + threadIdx.x) * 4;  // 1024 blocks covers 4*nW
  const float* src;
  ushort_t* dst;
  if (e < nW)            { src = Wi + e;          dst = Wcat + e; }
  else if (e < 2 * nW)   { src = Wg + (e - nW);   dst = Wcat + e; }
  else if (e < 3 * nW)   { src = Wo + (e - 2*nW); dst = Wcat + e; }
  else                   { src = Wout + (e - 3*nW); dst = WoutB + (e - 3*nW); }
  float4 v = *(const float4*)src;
  union { unsigned short us[4]; uint2 u; } p;
  p.us[0] = f2bf(v.x); p.us[1] = f2bf(v.y); p.us[2] = f2bf(v.z); p.us[3] = f2bf(v.w);
  *(uint2*)dst = p.u;
}

extern "C" void kernel_launch(void* const* d_in, const int* in_sizes, int n_in,
                              void* d_out, int out_size, void* d_ws, size_t ws_size,
                              hipStream_t stream) {
  const float* y    = (const float*)d_in[0];
  const float* ts   = (const float*)d_in[1];
  const float* Wi   = (const float*)d_in[2];
  // d_in[3] = Wf: computed-but-unused in reference -> skipped
  const float* Wg   = (const float*)d_in[4];
  const float* Wo   = (const float*)d_in[5];
  const float* Wout = (const float*)d_in[6];
  const float* bout = (const float*)d_in[7];
  const float* Wfc  = (const float*)d_in[8];
  const float* bfc  = (const float*)d_in[9];
  float* out = (float*)d_out;

  // workspace: only converted weights
  char* ws = (char*)d_ws;
  ushort_t* Wcat  = (ushort_t*)(ws);             // 1536*512*2 = 1572864
  ushort_t* WoutB = (ushort_t*)(ws + 1572864);   // 512*512*2  = 524288

  convw_kernel<<<1024, 256, 0, stream>>>(Wi, Wg, Wo, Wout, Wcat, WoutB);
  // ONE persistent kernel, barrier-free wave-local pipelined weight streaming.
  ode_persistent<<<256, 512, 0, stream>>>(y, Wcat, WoutB, bout, Wfc, bfc, ts, out);
}